// Round 6
// baseline (467.873 us; speedup 1.0000x reference)
//
#include <hip/hip_runtime.h>

// N=10000, E=50000, IN=32, H=64 (derived from in_sizes at launch).
//
// Algebra: theta[e] = sum_k ea[e,k]*W_k + B  (W_k[i,o] = nn_w[k, i*64+o])
//   agg[n,o] = sum_k sum_i G_k[n,i]*W_k[i,o] + sum_i G4[n,i]*B[i,o]
//   where G_k[n,:] = sum_{e:dst=n} ea[e,k]*h[src,:],  G4[n,:] = sum h[src,:]
// Per iter (2 dispatches):
//   D_a: gather G[N,320] (reads only h, L2-resident)  ||  gh[N,192] = h @ w_hh^T
//   D_b: m = relu([G|h] @ [W0..W3;B;root] + conv_b); gi = m @ w_ih^T; GRU -> h
// Prologue (1 dispatch): block 0 builds CSR entirely in LDS; other blocks do lin0.
// Round-4 lesson: grid.sync ~70-100us on 8-XCD MI355X -> kernel boundaries are the
// cheap global barrier (~11us). Round-5 lesson: dispatch count dominates; cut to 7.

#define AP 65   // a/m LDS stride: odd -> conflict-free transposed staging
#define WP 68   // w LDS stride: float4-aligned rows
#define GB 640  // gather blocks (2560 waves, ~4 nodes/wave)

__device__ __forceinline__ float sigmoidf_(float x) { return 1.0f / (1.0f + __expf(-x)); }
__device__ __forceinline__ float tanhf_(float x) { return 2.0f / (1.0f + __expf(-2.0f * x)) - 1.0f; }

// ---------------- prep: block 0 = LDS CSR build; blocks>=1 = lin0 -------------------
__global__ __launch_bounds__(1024) void prep_k(const float* __restrict__ x,
                                               const float* __restrict__ w0,
                                               const float* __restrict__ b0,
                                               const int* __restrict__ ei,
                                               const float4* __restrict__ ea,
                                               float* __restrict__ h,
                                               int* __restrict__ rowptr,
                                               int* __restrict__ esrc,
                                               float4* __restrict__ eattr,
                                               int N, int E) {
    extern __shared__ int cnt[];  // [N] ints (40KB at N=10000)
    __shared__ int part[1024];
    const int tid = threadIdx.x;
    if (blockIdx.x == 0) {
        for (int i = tid; i < N; i += 1024) cnt[i] = 0;
        __syncthreads();
        for (int e = tid; e < E; e += 1024) atomicAdd(&cnt[ei[E + e]], 1);
        __syncthreads();
        const int per = (N + 1023) >> 10;
        const int s0 = min(tid * per, N), e0 = min(s0 + per, N);
        int sum = 0;
        for (int i = s0; i < e0; ++i) sum += cnt[i];
        part[tid] = sum;
        __syncthreads();
        for (int d = 1; d < 1024; d <<= 1) {  // inclusive Hillis-Steele
            int u = (tid >= d) ? part[tid - d] : 0;
            __syncthreads();
            part[tid] += u;
            __syncthreads();
        }
        int off = part[tid] - sum;  // exclusive prefix of this thread's chunk
        for (int i = s0; i < e0; ++i) {
            int c = cnt[i];
            rowptr[i] = off;
            cnt[i] = off;  // becomes cursor
            off += c;
        }
        if (tid == 0) rowptr[N] = E;
        __syncthreads();
        for (int e = tid; e < E; e += 1024) {
            int d = ei[E + e];
            int pos = atomicAdd(&cnt[d], 1);
            esrc[pos] = ei[e];
            eattr[pos] = ea[e];
        }
    } else {
        int gid = (blockIdx.x - 1) * 1024 + tid;
        int gsz = (gridDim.x - 1) * 1024;
        for (int idx = gid; idx < N * 64; idx += gsz) {
            int n = idx >> 6, l = idx & 63;
            float acc = b0[l];
#pragma unroll
            for (int j = 0; j < 32; ++j) acc = fmaf(x[n * 32 + j], w0[j * 64 + l], acc);
            h[idx] = fmaxf(acc, 0.0f);
        }
    }
}

// ---------------- D_a: gather G (blocks < GB)  ||  gh = h @ w_hh^T (blocks >= GB) ---
__global__ __launch_bounds__(256) void gath_k(const int* __restrict__ rowptr,
                                              const int* __restrict__ esrc,
                                              const float4* __restrict__ eattr,
                                              const float* __restrict__ h,
                                              const float* __restrict__ w_hh,
                                              float* __restrict__ G,
                                              float* __restrict__ gh, int N) {
    const int tid = threadIdx.x, bid = blockIdx.x;
    if (bid < GB) {
        const int lane = tid & 63;
        int gw = (bid * 256 + tid) >> 6;
        const int nwaves = GB * 4;
        for (int n = gw; n < N; n += nwaves) {
            const int b = rowptr[n], e = rowptr[n + 1];
            float g0 = 0, g1 = 0, g2 = 0, g3 = 0, g4 = 0;
            int i = b;
            for (; i + 2 <= e; i += 2) {  // unroll-2: both loads in flight together
                int s0 = esrc[i], s1 = esrc[i + 1];
                float4 a0 = eattr[i], a1 = eattr[i + 1];
                float v0 = h[s0 * 64 + lane];
                float v1 = h[s1 * 64 + lane];
                g0 = fmaf(a0.x, v0, g0); g1 = fmaf(a0.y, v0, g1);
                g2 = fmaf(a0.z, v0, g2); g3 = fmaf(a0.w, v0, g3); g4 += v0;
                g0 = fmaf(a1.x, v1, g0); g1 = fmaf(a1.y, v1, g1);
                g2 = fmaf(a1.z, v1, g2); g3 = fmaf(a1.w, v1, g3); g4 += v1;
            }
            if (i < e) {
                int s0 = esrc[i];
                float4 a0 = eattr[i];
                float v0 = h[s0 * 64 + lane];
                g0 = fmaf(a0.x, v0, g0); g1 = fmaf(a0.y, v0, g1);
                g2 = fmaf(a0.z, v0, g2); g3 = fmaf(a0.w, v0, g3); g4 += v0;
            }
            float* gp = G + (size_t)n * 320 + lane;
            gp[0] = g0; gp[64] = g1; gp[128] = g2; gp[192] = g3; gp[256] = g4;
        }
    } else {
        __shared__ float a_lds[64 * AP];
        __shared__ float w_lds[64 * WP];
        const int n0 = (bid - GB) * 64;
        for (int idx = tid; idx < 4096; idx += 256) {
            int r = idx >> 6, j = idx & 63;
            int n = n0 + r;
            a_lds[j * AP + r] = (n < N) ? h[n * 64 + j] : 0.0f;
        }
        const int row_t = tid >> 4, col_t = tid & 15;
        const int r0 = row_t * 4, c0 = col_t * 4;
        float acc[3][4][4] = {};
#pragma unroll
        for (int s = 0; s < 3; ++s) {
            __syncthreads();
            int g0c = s * 64;
            for (int idx = tid; idx < 4096; idx += 256) {
                int c = idx >> 6, j = idx & 63;  // j fast: coalesced w_hh reads
                w_lds[j * WP + c] = w_hh[(g0c + c) * 64 + j];
            }
            __syncthreads();
#pragma unroll 4
            for (int j = 0; j < 64; ++j) {
                float av[4];
#pragma unroll
                for (int rr = 0; rr < 4; ++rr) av[rr] = a_lds[j * AP + r0 + rr];
                const float4 w4 = *(const float4*)(w_lds + j * WP + c0);
                const float wv[4] = {w4.x, w4.y, w4.z, w4.w};
#pragma unroll
                for (int rr = 0; rr < 4; ++rr)
#pragma unroll
                    for (int cc = 0; cc < 4; ++cc)
                        acc[s][rr][cc] = fmaf(av[rr], wv[cc], acc[s][rr][cc]);
            }
        }
#pragma unroll
        for (int s = 0; s < 3; ++s) {
#pragma unroll
            for (int rr = 0; rr < 4; ++rr) {
                int n = n0 + r0 + rr;
                if (n < N)
                    *(float4*)(gh + (size_t)n * 192 + s * 64 + c0) =
                        make_float4(acc[s][rr][0], acc[s][rr][1], acc[s][rr][2],
                                    acc[s][rr][3]);
            }
        }
    }
}

// ---------------- D_b: m = relu([G|h]@Wm + conv_b); gi = m@w_ih^T; GRU -> h ---------
__global__ __launch_bounds__(256) void mgru_k(const float* __restrict__ G,
                                              const float* __restrict__ nn_w,
                                              const float* __restrict__ nn_b,
                                              const float* __restrict__ root_w,
                                              const float* __restrict__ conv_b,
                                              const float* __restrict__ w_ih,
                                              const float* __restrict__ b_ih,
                                              const float* __restrict__ b_hh,
                                              const float* __restrict__ gh,
                                              float* __restrict__ h,
                                              float* __restrict__ out_final, int N) {
    __shared__ float a_lds[64 * AP];
    __shared__ float w_lds[64 * WP];
    __shared__ float m_lds[64 * AP];
    const int n0 = blockIdx.x * 64;
    const int tid = threadIdx.x;
    const int row_t = tid >> 4, col_t = tid & 15;
    const int r0 = row_t * 4, c0 = col_t * 4;

    // ---- GEMM1: m_pre[64,64], K=384 over chunks [G0|G1|G2|G3|G4|h] ----
    float accm[4][4] = {};
    for (int c = 0; c < 6; ++c) {
        __syncthreads();
        for (int idx = tid; idx < 4096; idx += 256) {
            int r = idx >> 6, j = idx & 63;
            int n = n0 + r;
            float v = 0.0f;
            if (n < N) v = (c < 5) ? G[(size_t)n * 320 + c * 64 + j] : h[(size_t)n * 64 + j];
            a_lds[j * AP + r] = v;
        }
        for (int idx = tid; idx < 4096; idx += 256) {
            int j = idx >> 6, cc = idx & 63;  // cc fast: coalesced
            float v;
            if (c < 4) v = nn_w[c * 4096 + j * 64 + cc];
            else if (c == 4) v = nn_b[j * 64 + cc];
            else v = root_w[j * 64 + cc];
            w_lds[j * WP + cc] = v;
        }
        __syncthreads();
#pragma unroll 4
        for (int j = 0; j < 64; ++j) {
            float av[4];
#pragma unroll
            for (int rr = 0; rr < 4; ++rr) av[rr] = a_lds[j * AP + r0 + rr];
            const float4 w4 = *(const float4*)(w_lds + j * WP + c0);
            const float wv[4] = {w4.x, w4.y, w4.z, w4.w};
#pragma unroll
            for (int rr = 0; rr < 4; ++rr)
#pragma unroll
                for (int cc = 0; cc < 4; ++cc)
                    accm[rr][cc] = fmaf(av[rr], wv[cc], accm[rr][cc]);
        }
    }
    // m = relu(m_pre + conv_b) -> m_lds transposed: m_lds[l][r]
#pragma unroll
    for (int cc = 0; cc < 4; ++cc) {
        float cb = conv_b[c0 + cc];
#pragma unroll
        for (int rr = 0; rr < 4; ++rr)
            m_lds[(c0 + cc) * AP + r0 + rr] = fmaxf(accm[rr][cc] + cb, 0.0f);
    }

    // ---- GEMM2: gi[64,192] = m @ w_ih^T, K=64 ----
    float accg[3][4][4] = {};
#pragma unroll
    for (int cb = 0; cb < 3; ++cb) {
        __syncthreads();  // first pass: m_lds visibility; later: w_lds reuse
        for (int idx = tid; idx < 4096; idx += 256) {
            int j = idx >> 6, cc = idx & 63;  // j fast: coalesced w_ih reads
            w_lds[j * WP + cc] = w_ih[(cb * 64 + cc) * 64 + j];
        }
        __syncthreads();
#pragma unroll 4
        for (int j = 0; j < 64; ++j) {
            float av[4];
#pragma unroll
            for (int rr = 0; rr < 4; ++rr) av[rr] = m_lds[j * AP + r0 + rr];
            const float4 w4 = *(const float4*)(w_lds + j * WP + c0);
            const float wv[4] = {w4.x, w4.y, w4.z, w4.w};
#pragma unroll
            for (int rr = 0; rr < 4; ++rr)
#pragma unroll
                for (int cc = 0; cc < 4; ++cc)
                    accg[cb][rr][cc] = fmaf(av[rr], wv[cc], accg[cb][rr][cc]);
        }
    }

    // ---- GRU elementwise epilogue ----
#pragma unroll
    for (int rr = 0; rr < 4; ++rr) {
        int n = n0 + r0 + rr;
        if (n >= N) continue;
        const float4 ghr4 = *(const float4*)(gh + (size_t)n * 192 + c0);
        const float4 ghz4 = *(const float4*)(gh + (size_t)n * 192 + 64 + c0);
        const float4 ghn4 = *(const float4*)(gh + (size_t)n * 192 + 128 + c0);
        const float4 hv4 = *(const float4*)(h + (size_t)n * 64 + c0);
        const float ghr[4] = {ghr4.x, ghr4.y, ghr4.z, ghr4.w};
        const float ghz[4] = {ghz4.x, ghz4.y, ghz4.z, ghz4.w};
        const float ghn[4] = {ghn4.x, ghn4.y, ghn4.z, ghn4.w};
        const float hv[4] = {hv4.x, hv4.y, hv4.z, hv4.w};
        float hnew[4];
#pragma unroll
        for (int cc = 0; cc < 4; ++cc) {
            int l = c0 + cc;
            float rg = sigmoidf_(accg[0][rr][cc] + b_ih[l] + ghr[cc] + b_hh[l]);
            float zg = sigmoidf_(accg[1][rr][cc] + b_ih[64 + l] + ghz[cc] + b_hh[64 + l]);
            float ng = tanhf_(accg[2][rr][cc] + b_ih[128 + l] + rg * (ghn[cc] + b_hh[128 + l]));
            hnew[cc] = (1.0f - zg) * ng + zg * hv[cc];
        }
        float4 o = make_float4(hnew[0], hnew[1], hnew[2], hnew[3]);
        *(float4*)(h + (size_t)n * 64 + c0) = o;
        if (out_final) *(float4*)(out_final + (size_t)n * 64 + c0) = o;
    }
}

extern "C" void kernel_launch(void* const* d_in, const int* in_sizes, int n_in,
                              void* d_out, int out_size, void* d_ws, size_t ws_size,
                              hipStream_t stream) {
    const float* x      = (const float*)d_in[0];
    const int*   ei     = (const int*)d_in[1];
    const float* ea     = (const float*)d_in[2];
    const float* lin0_w = (const float*)d_in[3];
    const float* lin0_b = (const float*)d_in[4];
    const float* nn_w   = (const float*)d_in[5];
    const float* nn_b   = (const float*)d_in[6];
    const float* root_w = (const float*)d_in[7];
    const float* conv_b = (const float*)d_in[8];
    const float* gw_ih  = (const float*)d_in[9];
    const float* gw_hh  = (const float*)d_in[10];
    const float* gb_ih  = (const float*)d_in[11];
    const float* gb_hh  = (const float*)d_in[12];

    const int N = in_sizes[0] / 32;
    const int E = in_sizes[1] / 2;
    const int RB = (N + 63) / 64;

    // workspace layout (16B-aligned: float4 arrays first)
    float* eattr = (float*)d_ws;                   // [E,4]
    float* G     = eattr + (size_t)E * 4;          // [N,320]
    float* gh    = G + (size_t)N * 320;            // [N,192]
    float* h     = gh + (size_t)N * 192;           // [N,64]
    int* rowptr  = (int*)(h + (size_t)N * 64);     // [N+1]
    int* esrc    = rowptr + (N + 1);               // [E]

    // D1: CSR build (block 0, LDS) + lin0 (blocks 1..)
    const int lin0_blocks = (N * 64 + 1023) / 1024;
    prep_k<<<1 + lin0_blocks, 1024, (size_t)N * 4, stream>>>(
        x, lin0_w, lin0_b, ei, (const float4*)ea, h, rowptr, esrc, (float4*)eattr, N, E);

    for (int it = 0; it < 3; ++it) {
        // D_a: gather G || gh GEMM (mixed-role blocks, both read only h)
        gath_k<<<GB + RB, 256, 0, stream>>>(rowptr, esrc, (const float4*)eattr, h,
                                            gw_hh, G, gh, N);
        // D_b: m-GEMM (K=384) + gi-GEMM + GRU
        mgru_k<<<RB, 256, 0, stream>>>(G, nn_w, nn_b, root_w, conv_b, gw_ih,
                                       gb_ih, gb_hh, gh, h,
                                       (it == 2) ? (float*)d_out : nullptr, N);
    }
}

// Round 7
// 338.646 us; speedup vs baseline: 1.3816x; 1.3816x over previous
//
#include <hip/hip_runtime.h>

// N=10000, E=50000, IN=32, H=64 (derived from in_sizes at launch).
//
// Algebra: theta[e] = sum_k ea[e,k]*W_k + B  (W_k[i,o] = nn_w[k, i*64+o])
//   agg[n,o] = sum_c G_c[n,:]@W_c + G4[n,:]@B, G_c[n,:] = sum_{e:dst=n} ea[e,c]*h[src,:]
// Iteration is node-local after reading h_old:
//   iter_k (one dispatch, 32 nodes/block): gather G(own rows) ->
//     m = relu([G|h]@[W0..W3;B;root] + conv_b) ->
//     gates = [m|h]@[w_ih;w_hh]^T (merged; gh never materialized) -> GRU -> h_new
// h ping-pongs between two buffers across iterations (kernel boundary = barrier).
// R4 lesson: grid.sync ~100us on 8-XCD MI355X -> use kernel boundaries (~11us).
// R6 lesson: single-block CSR build (150us) and 157-block GEMM chains starve the
// GPU -> keep every dispatch wide; prologue = 4 small parallel dispatches.

#define AP2 33  // a/m LDS stride (32 rows + 1): odd -> conflict-free
#define WP 68   // w LDS stride: float4-aligned rows

__device__ __forceinline__ float sigmoidf_(float x) { return 1.0f / (1.0f + __expf(-x)); }
__device__ __forceinline__ float tanhf_(float x) { return 2.0f / (1.0f + __expf(-2.0f * x)) - 1.0f; }

// ---------------- P0: zero dcnt + lin0 (h = relu(x@lin0_w+b)) -----------------------
__global__ __launch_bounds__(256) void zlin0_k(const float* __restrict__ x,
                                               const float* __restrict__ w,
                                               const float* __restrict__ b,
                                               float* __restrict__ h,
                                               int* __restrict__ dcnt, int N) {
    int gid = blockIdx.x * 256 + threadIdx.x;
    int gsz = gridDim.x * 256;
    for (int i = gid; i < N; i += gsz) dcnt[i] = 0;
    for (int idx = gid; idx < N * 64; idx += gsz) {
        int n = idx >> 6, l = idx & 63;
        float acc = b[l];
#pragma unroll
        for (int j = 0; j < 32; ++j) acc = fmaf(x[n * 32 + j], w[j * 64 + l], acc);
        h[idx] = fmaxf(acc, 0.0f);
    }
}

// ---------------- CSR build (parallel, 3 small dispatches) --------------------------
__global__ __launch_bounds__(256) void count_k(const int* __restrict__ ei,
                                               int* __restrict__ dcnt, int E) {
    int e = blockIdx.x * 256 + threadIdx.x;
    if (e < E) atomicAdd(dcnt + ei[E + e], 1);
}

__global__ __launch_bounds__(1024) void scan_k(const int* __restrict__ dcnt,
                                               int* __restrict__ rowptr,
                                               int* __restrict__ cursor, int N) {
    __shared__ int part[1024];
    const int t = threadIdx.x;
    const int per = (N + 1023) >> 10;
    const int s0 = t * per;
    const int e0 = min(s0 + per, N);
    int sum = 0;
    for (int i = s0; i < e0; ++i) sum += dcnt[i];
    part[t] = sum;
    __syncthreads();
    for (int d = 1; d < 1024; d <<= 1) {
        int u = (t >= d) ? part[t - d] : 0;
        __syncthreads();
        part[t] += u;
        __syncthreads();
    }
    int off = part[t] - sum;
    for (int i = s0; i < e0; ++i) {
        rowptr[i] = off;
        cursor[i] = off;
        off += dcnt[i];
    }
    if (e0 == N && s0 < N) rowptr[N] = off;
}

__global__ __launch_bounds__(256) void fill_k(const int* __restrict__ ei,
                                              const float4* __restrict__ ea,
                                              int* __restrict__ cursor,
                                              int* __restrict__ esrc,
                                              float4* __restrict__ eattr, int E) {
    int e = blockIdx.x * 256 + threadIdx.x;
    if (e >= E) return;
    int d = ei[E + e];
    int pos = atomicAdd(cursor + d, 1);
    esrc[pos] = ei[e];
    eattr[pos] = ea[e];
}

// ---------------- iter_k: one dispatch per GNN iteration ----------------------------
// Block owns 32 nodes. Phases: A gather G -> B m-GEMM(K=384) -> C [m|h]-GEMM(K=128,
// merged ih+hh) -> D GRU epilogue. All node-local given h_old.
__global__ __launch_bounds__(256) void iter_k(const float* __restrict__ h_old,
                                              float* __restrict__ h_new,
                                              const int* __restrict__ rowptr,
                                              const int* __restrict__ esrc,
                                              const float4* __restrict__ eattr,
                                              float* __restrict__ G,
                                              const float* __restrict__ nn_w,
                                              const float* __restrict__ nn_b,
                                              const float* __restrict__ root_w,
                                              const float* __restrict__ conv_b,
                                              const float* __restrict__ w_ih,
                                              const float* __restrict__ w_hh,
                                              const float* __restrict__ b_ih,
                                              const float* __restrict__ b_hh,
                                              float* __restrict__ out_final, int N) {
    __shared__ float a_lds[64 * AP2];      // A chunk transposed [K=64][row=32]
    __shared__ float m_lds[64 * AP2];      // m transposed
    __shared__ float w_lds[2 * 64 * WP];   // W tile(s)
    const int tid = threadIdx.x;
    const int n0 = blockIdx.x * 32;
    const int lane = tid & 63, wv = tid >> 6;

    // ---- Phase A: gather G for own 32 nodes (wave wv -> 8 consecutive nodes) ----
    for (int i = 0; i < 8; ++i) {
        int n = n0 + wv * 8 + i;
        if (n >= N) break;
        int b = rowptr[n], e = rowptr[n + 1];
        float g0 = 0.f, g1 = 0.f, g2 = 0.f, g3 = 0.f, g4 = 0.f;
        int t = b;
        for (; t + 2 <= e; t += 2) {  // unroll-2: both gathers in flight
            int s0 = esrc[t], s1 = esrc[t + 1];
            float4 a0 = eattr[t], a1 = eattr[t + 1];
            float v0 = h_old[(size_t)s0 * 64 + lane];
            float v1 = h_old[(size_t)s1 * 64 + lane];
            g0 = fmaf(a0.x, v0, g0); g1 = fmaf(a0.y, v0, g1);
            g2 = fmaf(a0.z, v0, g2); g3 = fmaf(a0.w, v0, g3); g4 += v0;
            g0 = fmaf(a1.x, v1, g0); g1 = fmaf(a1.y, v1, g1);
            g2 = fmaf(a1.z, v1, g2); g3 = fmaf(a1.w, v1, g3); g4 += v1;
        }
        if (t < e) {
            int s0 = esrc[t];
            float4 a0 = eattr[t];
            float v0 = h_old[(size_t)s0 * 64 + lane];
            g0 = fmaf(a0.x, v0, g0); g1 = fmaf(a0.y, v0, g1);
            g2 = fmaf(a0.z, v0, g2); g3 = fmaf(a0.w, v0, g3); g4 += v0;
        }
        float* gp = G + (size_t)n * 320 + lane;
        gp[0] = g0; gp[64] = g1; gp[128] = g2; gp[192] = g3; gp[256] = g4;
    }
    __syncthreads();  // G writes drained (vmcnt) before GEMM1 reads them back (L2-hot)

    const int row_t = tid >> 4, col_t = tid & 15;
    const int r0 = row_t * 2, c0 = col_t * 4;

    // ---- Phase B: m_pre[32,64] = [G0|G1|G2|G3|G4|h] @ [W0..W3;B;root], K=384 ----
    float accm[2][4] = {};
    for (int c = 0; c < 6; ++c) {
        __syncthreads();  // protect a_lds/w_lds from previous chunk's readers
        for (int idx = tid; idx < 2048; idx += 256) {
            int r = idx >> 6, j = idx & 63;
            int n = n0 + r;
            float v = 0.f;
            if (n < N)
                v = (c < 5) ? G[(size_t)n * 320 + c * 64 + j] : h_old[(size_t)n * 64 + j];
            a_lds[j * AP2 + r] = v;
        }
        for (int idx = tid; idx < 4096; idx += 256) {
            int j = idx >> 6, cc = idx & 63;  // cc fast: coalesced
            float v;
            if (c < 4) v = nn_w[c * 4096 + j * 64 + cc];
            else if (c == 4) v = nn_b[j * 64 + cc];
            else v = root_w[j * 64 + cc];
            w_lds[j * WP + cc] = v;
        }
        __syncthreads();
#pragma unroll 8
        for (int j = 0; j < 64; ++j) {
            float a0 = a_lds[j * AP2 + r0], a1 = a_lds[j * AP2 + r0 + 1];
            const float4 w4 = *(const float4*)(w_lds + j * WP + c0);
            accm[0][0] = fmaf(a0, w4.x, accm[0][0]);
            accm[0][1] = fmaf(a0, w4.y, accm[0][1]);
            accm[0][2] = fmaf(a0, w4.z, accm[0][2]);
            accm[0][3] = fmaf(a0, w4.w, accm[0][3]);
            accm[1][0] = fmaf(a1, w4.x, accm[1][0]);
            accm[1][1] = fmaf(a1, w4.y, accm[1][1]);
            accm[1][2] = fmaf(a1, w4.z, accm[1][2]);
            accm[1][3] = fmaf(a1, w4.w, accm[1][3]);
        }
    }
    // NOTE: a_lds now holds h_old chunk (c==5) -- kept live for Phase C and D.

    // m = relu(m_pre + conv_b), store transposed
#pragma unroll
    for (int cc = 0; cc < 4; ++cc) {
        float cb = conv_b[c0 + cc];
        m_lds[(c0 + cc) * AP2 + r0] = fmaxf(accm[0][cc] + cb, 0.f);
        m_lds[(c0 + cc) * AP2 + r0 + 1] = fmaxf(accm[1][cc] + cb, 0.f);
    }

    // ---- Phase C: gates[32,192] = m @ w_ih^T + h @ w_hh^T (n-gate parts separate) --
    // acc2[0]=r (merged), acc2[1]=z (merged), acc2[2]=gi_n, acc2[3]=gh_n
    float acc2[4][2][4] = {};
#pragma unroll
    for (int cb = 0; cb < 3; ++cb) {
        const int di = cb;
        const int dh = (cb == 2) ? 3 : cb;
        __syncthreads();  // cb=0: m_lds visible + chunk-5 readers done; else w_lds reuse
        for (int idx = tid; idx < 4096; idx += 256) {
            int j = idx >> 6, cc = idx & 63;  // j fast: coalesced row reads
            w_lds[j * WP + cc] = w_ih[(cb * 64 + cc) * 64 + j];
            w_lds[64 * WP + j * WP + cc] = w_hh[(cb * 64 + cc) * 64 + j];
        }
        __syncthreads();
#pragma unroll 4
        for (int j = 0; j < 64; ++j) {
            float m0 = m_lds[j * AP2 + r0], m1 = m_lds[j * AP2 + r0 + 1];
            float h0 = a_lds[j * AP2 + r0], h1 = a_lds[j * AP2 + r0 + 1];
            const float4 wi = *(const float4*)(w_lds + j * WP + c0);
            const float4 wh = *(const float4*)(w_lds + 64 * WP + j * WP + c0);
            acc2[di][0][0] = fmaf(m0, wi.x, acc2[di][0][0]);
            acc2[di][0][1] = fmaf(m0, wi.y, acc2[di][0][1]);
            acc2[di][0][2] = fmaf(m0, wi.z, acc2[di][0][2]);
            acc2[di][0][3] = fmaf(m0, wi.w, acc2[di][0][3]);
            acc2[di][1][0] = fmaf(m1, wi.x, acc2[di][1][0]);
            acc2[di][1][1] = fmaf(m1, wi.y, acc2[di][1][1]);
            acc2[di][1][2] = fmaf(m1, wi.z, acc2[di][1][2]);
            acc2[di][1][3] = fmaf(m1, wi.w, acc2[di][1][3]);
            acc2[dh][0][0] = fmaf(h0, wh.x, acc2[dh][0][0]);
            acc2[dh][0][1] = fmaf(h0, wh.y, acc2[dh][0][1]);
            acc2[dh][0][2] = fmaf(h0, wh.z, acc2[dh][0][2]);
            acc2[dh][0][3] = fmaf(h0, wh.w, acc2[dh][0][3]);
            acc2[dh][1][0] = fmaf(h1, wh.x, acc2[dh][1][0]);
            acc2[dh][1][1] = fmaf(h1, wh.y, acc2[dh][1][1]);
            acc2[dh][1][2] = fmaf(h1, wh.z, acc2[dh][1][2]);
            acc2[dh][1][3] = fmaf(h1, wh.w, acc2[dh][1][3]);
        }
    }

    // ---- Phase D: GRU elementwise -> h_new (+ out on final iteration) ----
#pragma unroll
    for (int rr = 0; rr < 2; ++rr) {
        int n = n0 + r0 + rr;
        if (n >= N) continue;
        float hnew[4];
#pragma unroll
        for (int cc = 0; cc < 4; ++cc) {
            int l = c0 + cc;
            float hvv = a_lds[l * AP2 + r0 + rr];  // h_old own value (still in LDS)
            float r = sigmoidf_(acc2[0][rr][cc] + b_ih[l] + b_hh[l]);
            float z = sigmoidf_(acc2[1][rr][cc] + b_ih[64 + l] + b_hh[64 + l]);
            float ng = tanhf_(acc2[2][rr][cc] + b_ih[128 + l] +
                              r * (acc2[3][rr][cc] + b_hh[128 + l]));
            hnew[cc] = (1.f - z) * ng + z * hvv;
        }
        float4 o = make_float4(hnew[0], hnew[1], hnew[2], hnew[3]);
        *(float4*)(h_new + (size_t)n * 64 + c0) = o;
        if (out_final) *(float4*)(out_final + (size_t)n * 64 + c0) = o;
    }
}

extern "C" void kernel_launch(void* const* d_in, const int* in_sizes, int n_in,
                              void* d_out, int out_size, void* d_ws, size_t ws_size,
                              hipStream_t stream) {
    const float* x      = (const float*)d_in[0];
    const int*   ei     = (const int*)d_in[1];
    const float* ea     = (const float*)d_in[2];
    const float* lin0_w = (const float*)d_in[3];
    const float* lin0_b = (const float*)d_in[4];
    const float* nn_w   = (const float*)d_in[5];
    const float* nn_b   = (const float*)d_in[6];
    const float* root_w = (const float*)d_in[7];
    const float* conv_b = (const float*)d_in[8];
    const float* gw_ih  = (const float*)d_in[9];
    const float* gw_hh  = (const float*)d_in[10];
    const float* gb_ih  = (const float*)d_in[11];
    const float* gb_hh  = (const float*)d_in[12];

    const int N = in_sizes[0] / 32;
    const int E = in_sizes[1] / 2;

    // workspace layout (16B-aligned float4 arrays first)
    float* eattr = (float*)d_ws;                   // [E,4]
    float* G     = eattr + (size_t)E * 4;          // [N,320]
    float* hA    = G + (size_t)N * 320;            // [N,64]
    float* hB    = hA + (size_t)N * 64;            // [N,64]
    int* rowptr  = (int*)(hB + (size_t)N * 64);    // [N+1]
    int* cursor  = rowptr + (N + 1);               // [N]
    int* esrc    = cursor + N;                     // [E]
    int* dcnt    = esrc + E;                       // [N]

    // prologue: 4 wide dispatches
    zlin0_k<<<(N * 64 + 255) / 256, 256, 0, stream>>>(x, lin0_w, lin0_b, hA, dcnt, N);
    count_k<<<(E + 255) / 256, 256, 0, stream>>>(ei, dcnt, E);
    scan_k<<<1, 1024, 0, stream>>>(dcnt, rowptr, cursor, N);
    fill_k<<<(E + 255) / 256, 256, 0, stream>>>(ei, (const float4*)ea, cursor, esrc,
                                                (float4*)eattr, E);

    const int TB = (N + 31) / 32;
    float* hbuf[2] = {hA, hB};
    for (int it = 0; it < 3; ++it) {
        iter_k<<<TB, 256, 0, stream>>>(hbuf[it & 1], hbuf[(it + 1) & 1], rowptr, esrc,
                                       (const float4*)eattr, G, nn_w, nn_b, root_w,
                                       conv_b, gw_ih, gw_hh, gb_ih, gb_hh,
                                       (it == 2) ? (float*)d_out : nullptr, N);
    }
}

// Round 8
// 252.394 us; speedup vs baseline: 1.8537x; 1.3417x over previous
//
#include <hip/hip_runtime.h>

// N=10000, E=50000, IN=32, H=64 (derived from in_sizes at launch).
//
// Algebra: theta[e] = sum_k ea[e,k]*W_k + B  (W_k[i,o] = nn_w[k, i*64+o])
//   agg[n,o] = sum_c G_c[n,:]@W_c + G4[n,:]@B, G_c[n,:] = sum_{e:dst=n} ea[e,c]*h[src,:]
// Iteration is node-local after reading h_old -> ONE dispatch per iteration:
//   iter_k (16 nodes/block, 625 blocks): gather G into LDS ->
//     m = relu([G|h]@[W0..W3;B;root] + conv_b) ->
//     gates = [m|h]@[w_ih;w_hh]^T (merged, 6 reg-prefetched tiles) -> GRU -> h_new
// h ping-pongs between two buffers (kernel boundary = the cheap global barrier).
// R4 lesson: grid.sync ~100us on MI355X. R6 lesson: never single-block CSR.
// R7 lesson: 313 blocks = 11% occupancy = latency death; this round: 625 blocks,
// 47.9KB LDS (3/CU), G in LDS (no global round-trip), reg-prefetched W tiles.

#define GP 17   // G/m LDS row stride (16+1): odd -> conflict-free
#define WP 68   // w LDS row stride: float4-aligned

__device__ __forceinline__ float sigmoidf_(float x) { return 1.0f / (1.0f + __expf(-x)); }
__device__ __forceinline__ float tanhf_(float x) { return 2.0f / (1.0f + __expf(-2.0f * x)) - 1.0f; }

// ---------------- P0: zero dcnt + lin0 (h = relu(x@lin0_w+b)) -----------------------
__global__ __launch_bounds__(256) void zlin0_k(const float* __restrict__ x,
                                               const float* __restrict__ w,
                                               const float* __restrict__ b,
                                               float* __restrict__ h,
                                               int* __restrict__ dcnt, int N) {
    int gid = blockIdx.x * 256 + threadIdx.x;
    int gsz = gridDim.x * 256;
    for (int i = gid; i < N; i += gsz) dcnt[i] = 0;
    for (int idx = gid; idx < N * 64; idx += gsz) {
        int n = idx >> 6, l = idx & 63;
        float acc = b[l];
#pragma unroll
        for (int j = 0; j < 32; ++j) acc = fmaf(x[n * 32 + j], w[j * 64 + l], acc);
        h[idx] = fmaxf(acc, 0.0f);
    }
}

// ---------------- CSR build (parallel, 3 small dispatches) --------------------------
__global__ __launch_bounds__(256) void count_k(const int* __restrict__ ei,
                                               int* __restrict__ dcnt, int E) {
    int e = blockIdx.x * 256 + threadIdx.x;
    if (e < E) atomicAdd(dcnt + ei[E + e], 1);
}

__global__ __launch_bounds__(1024) void scan_k(const int* __restrict__ dcnt,
                                               int* __restrict__ rowptr,
                                               int* __restrict__ cursor, int N) {
    __shared__ int part[1024];
    const int t = threadIdx.x;
    const int per = (N + 1023) >> 10;
    const int s0 = t * per;
    const int e0 = min(s0 + per, N);
    int sum = 0;
    for (int i = s0; i < e0; ++i) sum += dcnt[i];
    part[t] = sum;
    __syncthreads();
    for (int d = 1; d < 1024; d <<= 1) {
        int u = (t >= d) ? part[t - d] : 0;
        __syncthreads();
        part[t] += u;
        __syncthreads();
    }
    int off = part[t] - sum;
    for (int i = s0; i < e0; ++i) {
        rowptr[i] = off;
        cursor[i] = off;
        off += dcnt[i];
    }
    if (e0 == N && s0 < N) rowptr[N] = off;
}

__global__ __launch_bounds__(256) void fill_k(const int* __restrict__ ei,
                                              const float4* __restrict__ ea,
                                              int* __restrict__ cursor,
                                              int* __restrict__ esrc,
                                              float4* __restrict__ eattr, int E) {
    int e = blockIdx.x * 256 + threadIdx.x;
    if (e >= E) return;
    int d = ei[E + e];
    int pos = atomicAdd(cursor + d, 1);
    esrc[pos] = ei[e];
    eattr[pos] = ea[e];
}

// ---------------- iter_k: one dispatch per GNN iteration ----------------------------
// Block owns 16 nodes. G_lds rows 0..319 = gathered G chunks, rows 320..383 = own h.
// 12 weight tiles (all linear base[idx] loads) register-prefetched one round ahead.
__global__ __launch_bounds__(256) void iter_k(const float* __restrict__ h_old,
                                              float* __restrict__ h_new,
                                              const int* __restrict__ rowptr,
                                              const int* __restrict__ esrc,
                                              const float4* __restrict__ eattr,
                                              const float* __restrict__ nn_w,
                                              const float* __restrict__ nn_b,
                                              const float* __restrict__ root_w,
                                              const float* __restrict__ conv_b,
                                              const float* __restrict__ w_ih,
                                              const float* __restrict__ w_hh,
                                              const float* __restrict__ b_ih,
                                              const float* __restrict__ b_hh,
                                              float* __restrict__ out_final, int N) {
    __shared__ float G_lds[384 * GP];   // 26.1KB
    __shared__ float m_lds[64 * GP];    // 4.4KB
    __shared__ float w_lds[64 * WP];    // 17.4KB   total 47.9KB -> 3 blocks/CU
    const int tid = threadIdx.x;
    const int n0 = blockIdx.x * 16;
    const int lane = tid & 63, wv = tid >> 6;

    // prefetch weight tile 0 (nn_w[0]) into registers (issues early, consumed late)
    float wreg[16];
#pragma unroll
    for (int k = 0; k < 16; ++k) wreg[k] = nn_w[k * 256 + tid];

    // stage own h rows transposed -> G_lds rows 320..383
#pragma unroll
    for (int k = 0; k < 4; ++k) {
        int idx = k * 256 + tid;
        int r = idx >> 6, j = idx & 63;
        int n = n0 + r;
        G_lds[(320 + j) * GP + r] = (n < N) ? h_old[(size_t)n * 64 + j] : 0.f;
    }

    // ---- Phase A: gather own 16 nodes (wave wv -> rows wv*4..wv*4+3) ----
#pragma unroll
    for (int i = 0; i < 4; ++i) {
        int r = wv * 4 + i;
        int n = n0 + r;
        float g0 = 0.f, g1 = 0.f, g2 = 0.f, g3 = 0.f, g4 = 0.f;
        if (n < N) {
            int b = rowptr[n], e = rowptr[n + 1];
            int t = b;
            for (; t + 2 <= e; t += 2) {  // unroll-2: both gathers in flight
                int s0 = esrc[t], s1 = esrc[t + 1];
                float4 a0 = eattr[t], a1 = eattr[t + 1];
                float v0 = h_old[(size_t)s0 * 64 + lane];
                float v1 = h_old[(size_t)s1 * 64 + lane];
                g0 = fmaf(a0.x, v0, g0); g1 = fmaf(a0.y, v0, g1);
                g2 = fmaf(a0.z, v0, g2); g3 = fmaf(a0.w, v0, g3); g4 += v0;
                g0 = fmaf(a1.x, v1, g0); g1 = fmaf(a1.y, v1, g1);
                g2 = fmaf(a1.z, v1, g2); g3 = fmaf(a1.w, v1, g3); g4 += v1;
            }
            if (t < e) {
                int s0 = esrc[t];
                float4 a0 = eattr[t];
                float v0 = h_old[(size_t)s0 * 64 + lane];
                g0 = fmaf(a0.x, v0, g0); g1 = fmaf(a0.y, v0, g1);
                g2 = fmaf(a0.z, v0, g2); g3 = fmaf(a0.w, v0, g3); g4 += v0;
            }
        }
        G_lds[lane * GP + r] = g0;
        G_lds[(64 + lane) * GP + r] = g1;
        G_lds[(128 + lane) * GP + r] = g2;
        G_lds[(192 + lane) * GP + r] = g3;
        G_lds[(256 + lane) * GP + r] = g4;
    }

    const int row_t = tid >> 4, col_t = tid & 15;
    const int c0 = col_t * 4;

    // ---- Phase B: m_pre[16,64] = [G0..G4|h] @ [W0..W3;B;root], K=384, 6 rounds ----
    float accm[4] = {0.f, 0.f, 0.f, 0.f};
#pragma unroll
    for (int c = 0; c < 6; ++c) {
        __syncthreads();  // c=0: gather+h-stage done; else: prev FMA done with w_lds
#pragma unroll
        for (int k = 0; k < 16; ++k) {
            int idx = k * 256 + tid;
            w_lds[(idx >> 6) * WP + (idx & 63)] = wreg[k];
        }
        {   // prefetch next tile (c+1): 1..3 nn_w, 4 nn_b, 5 root_w, 6 w_ih[0]
            const float* base = (c < 3) ? nn_w + (c + 1) * 4096
                              : (c == 3) ? nn_b
                              : (c == 4) ? root_w
                              : w_ih;
#pragma unroll
            for (int k = 0; k < 16; ++k) wreg[k] = base[k * 256 + tid];
        }
        __syncthreads();
#pragma unroll 8
        for (int j = 0; j < 64; ++j) {
            float a = G_lds[(c * 64 + j) * GP + row_t];
            const float4 w4 = *(const float4*)(w_lds + j * WP + c0);
            accm[0] = fmaf(a, w4.x, accm[0]);
            accm[1] = fmaf(a, w4.y, accm[1]);
            accm[2] = fmaf(a, w4.z, accm[2]);
            accm[3] = fmaf(a, w4.w, accm[3]);
        }
    }

    // m = relu(m_pre + conv_b) -> m_lds transposed
#pragma unroll
    for (int cc = 0; cc < 4; ++cc)
        m_lds[(c0 + cc) * GP + row_t] = fmaxf(accm[cc] + conv_b[c0 + cc], 0.f);

    // ---- Phase C: gates[16,192] = m@w_ih^T + h@w_hh^T, 6 transposed tiles ----
    // t: 0,1,2 = ih r,z,n ; 3,4,5 = hh r,z,n.  r/z accumulate shared; n kept split.
    float acc2[4][4] = {};
#pragma unroll
    for (int t = 0; t < 6; ++t) {
        __syncthreads();  // t=0 also orders m_lds writes before reads
#pragma unroll
        for (int k = 0; k < 16; ++k) {
            int idx = k * 256 + tid;
            w_lds[(idx & 63) * WP + (idx >> 6)] = wreg[k];  // transposed store
        }
        if (t < 5) {
            const float* base = (t < 2) ? w_ih + (t + 1) * 4096 : w_hh + (t - 2) * 4096;
#pragma unroll
            for (int k = 0; k < 16; ++k) wreg[k] = base[k * 256 + tid];
        }
        __syncthreads();
        const int dst = (t < 3) ? t : ((t == 5) ? 3 : t - 3);  // constant per unrolled t
        const bool useM = (t < 3);
#pragma unroll 8
        for (int j = 0; j < 64; ++j) {
            float a = useM ? m_lds[j * GP + row_t] : G_lds[(320 + j) * GP + row_t];
            const float4 w4 = *(const float4*)(w_lds + j * WP + c0);
            acc2[dst][0] = fmaf(a, w4.x, acc2[dst][0]);
            acc2[dst][1] = fmaf(a, w4.y, acc2[dst][1]);
            acc2[dst][2] = fmaf(a, w4.z, acc2[dst][2]);
            acc2[dst][3] = fmaf(a, w4.w, acc2[dst][3]);
        }
    }

    // ---- Phase D: GRU elementwise -> h_new ----
    int n = n0 + row_t;
    if (n < N) {
        float hnew[4];
#pragma unroll
        for (int cc = 0; cc < 4; ++cc) {
            int l = c0 + cc;
            float hv = G_lds[(320 + l) * GP + row_t];
            float r = sigmoidf_(acc2[0][cc] + b_ih[l] + b_hh[l]);
            float z = sigmoidf_(acc2[1][cc] + b_ih[64 + l] + b_hh[64 + l]);
            float ng = tanhf_(acc2[2][cc] + b_ih[128 + l] +
                              r * (acc2[3][cc] + b_hh[128 + l]));
            hnew[cc] = (1.f - z) * ng + z * hv;
        }
        float4 o = make_float4(hnew[0], hnew[1], hnew[2], hnew[3]);
        *(float4*)(h_new + (size_t)n * 64 + c0) = o;
        if (out_final) *(float4*)(out_final + (size_t)n * 64 + c0) = o;
    }
}

extern "C" void kernel_launch(void* const* d_in, const int* in_sizes, int n_in,
                              void* d_out, int out_size, void* d_ws, size_t ws_size,
                              hipStream_t stream) {
    const float* x      = (const float*)d_in[0];
    const int*   ei     = (const int*)d_in[1];
    const float* ea     = (const float*)d_in[2];
    const float* lin0_w = (const float*)d_in[3];
    const float* lin0_b = (const float*)d_in[4];
    const float* nn_w   = (const float*)d_in[5];
    const float* nn_b   = (const float*)d_in[6];
    const float* root_w = (const float*)d_in[7];
    const float* conv_b = (const float*)d_in[8];
    const float* gw_ih  = (const float*)d_in[9];
    const float* gw_hh  = (const float*)d_in[10];
    const float* gb_ih  = (const float*)d_in[11];
    const float* gb_hh  = (const float*)d_in[12];

    const int N = in_sizes[0] / 32;
    const int E = in_sizes[1] / 2;

    // workspace layout (16B-aligned float4 arrays first)
    float* eattr = (float*)d_ws;                   // [E,4]
    float* hA    = eattr + (size_t)E * 4;          // [N,64]
    float* hB    = hA + (size_t)N * 64;            // [N,64]
    int* rowptr  = (int*)(hB + (size_t)N * 64);    // [N+1]
    int* cursor  = rowptr + (N + 1);               // [N]
    int* esrc    = cursor + N;                     // [E]
    int* dcnt    = esrc + E;                       // [N]

    // prologue: 4 wide dispatches
    zlin0_k<<<(N * 64 + 255) / 256, 256, 0, stream>>>(x, lin0_w, lin0_b, hA, dcnt, N);
    count_k<<<(E + 255) / 256, 256, 0, stream>>>(ei, dcnt, E);
    scan_k<<<1, 1024, 0, stream>>>(dcnt, rowptr, cursor, N);
    fill_k<<<(E + 255) / 256, 256, 0, stream>>>(ei, (const float4*)ea, cursor, esrc,
                                                (float4*)eattr, E);

    const int TB = (N + 15) / 16;
    float* hbuf[2] = {hA, hB};
    for (int it = 0; it < 3; ++it) {
        iter_k<<<TB, 256, 0, stream>>>(hbuf[it & 1], hbuf[(it + 1) & 1], rowptr, esrc,
                                       (const float4*)eattr, nn_w, nn_b, root_w,
                                       conv_b, gw_ih, gw_hh, gb_ih, gb_hh,
                                       (it == 2) ? (float*)d_out : nullptr, N);
    }
}